// Round 2
// baseline (394.642 us; speedup 1.0000x reference)
//
#include <hip/hip_runtime.h>
#include <hip/hip_fp16.h>
#include <math.h>

#define N_NODES 100000
#define N_PAD   100352          // scan width (multiple of 4096-chunk coverage)
#define N_EDGES 1600000
#define IN_DIM 128
#define F_DIM 128      // HEADS*OUT_DIM
#define NEG_SLOPE 0.2f

#define GB 1563                 // gemm blocks: ceil(100000/64)
#define HB 200                  // histogram blocks fused after gemm blocks
#define EPH 8000                // edges per histogram block (HB*EPH == N_EDGES)
#define SB 200                  // scatter blocks
#define EPS 8000                // edges per scatter block

#define SC_CHUNK 4096
#define SC_NB ((N_PAD + SC_CHUNK - 1) / SC_CHUNK)   // 25 (fits one wave in k_scant)
#define CSR_CAP (N_EDGES + 3 * N_PAD + 64)          // pad-to-4 slots (<=3/node)

typedef short v8s __attribute__((ext_vector_type(8)));
typedef float v4f __attribute__((ext_vector_type(4)));

static __device__ __forceinline__ unsigned short f2bf(float f) {
    unsigned u = __float_as_uint(f);
    u += 0x7fffu + ((u >> 16) & 1u);
    return (unsigned short)(u >> 16);
}
static __device__ __forceinline__ float lo2f(unsigned u) { return __uint_as_float(u << 16); }
static __device__ __forceinline__ float hi2f(unsigned u) { return __uint_as_float(u & 0xffff0000u); }

// ---------------- fused: GEMM tiles (blocks < GB) + degree hist (blocks >= GB)
// GEMM: h16 = bf16(x @ W) via MFMA, fused a_src/a_dst epilogue. W converted
// f32->bf16 during LDS staging (64KB, L2-resident across the 1563 blocks).
// Hist: deg[d]++ over all edges; rides for free under the BW-bound GEMM.
__global__ __launch_bounds__(256) void k_main(const float* __restrict__ x,
                                              const float* __restrict__ W,
                                              const int* __restrict__ ei_dst,
                                              unsigned short* __restrict__ h16,
                                              const float* __restrict__ att_src,
                                              const float* __restrict__ att_dst,
                                              float* __restrict__ a_src,
                                              float* __restrict__ a_dst,
                                              int* __restrict__ deg) {
    if (blockIdx.x >= GB) {               // ---- histogram part ----
        int hb = blockIdx.x - GB;
        const int4* p = (const int4*)(ei_dst + hb * EPH);
        for (int i = threadIdx.x; i < EPH / 4; i += 256) {
            int4 d = p[i];
            atomicAdd(&deg[d.x], 1);
            atomicAdd(&deg[d.y], 1);
            atomicAdd(&deg[d.z], 1);
            atomicAdd(&deg[d.w], 1);
        }
        return;
    }

    __shared__ unsigned short As[64][136];    // [row][k]
    __shared__ unsigned short Bs[128][136];   // [n][k]
    __shared__ float attl[256];               // [0..127]=att_src, [128..255]=att_dst
    const int t  = threadIdx.x;
    const int n0 = blockIdx.x * 64;

    attl[t] = (t < 128) ? att_src[t] : att_dst[t - 128];

    {
        int row = t >> 2, k0 = (t & 3) * 32;
        int n = n0 + row;
        #pragma unroll
        for (int i = 0; i < 4; i++) {
            float4 va = make_float4(0.f,0.f,0.f,0.f), vb = va;
            if (n < N_NODES) {
                const float* p = x + (size_t)n * IN_DIM + k0 + i * 8;
                va = *(const float4*)p;
                vb = *(const float4*)(p + 4);
            }
            uint4 u;
            u.x = f2bf(va.x) | ((unsigned)f2bf(va.y) << 16);
            u.y = f2bf(va.z) | ((unsigned)f2bf(va.w) << 16);
            u.z = f2bf(vb.x) | ((unsigned)f2bf(vb.y) << 16);
            u.w = f2bf(vb.z) | ((unsigned)f2bf(vb.w) << 16);
            *(uint4*)&As[row][k0 + i * 8] = u;
        }
    }
    {   // Bs[n][k] = bf16(W[k*128+n]); coalesced f32 reads, 4-way LDS write conflict ok
        #pragma unroll
        for (int i = 0; i < 64; i++) {
            int j = (i << 8) + t;
            int k = j >> 7, n = j & 127;
            Bs[n][k] = f2bf(W[j]);
        }
    }
    __syncthreads();

    const int w = t >> 6, lane = t & 63;
    const int mr = lane & 15, quad = lane >> 4;
    const int m0 = w * 16;

    v4f acc[8];
    #pragma unroll
    for (int nt = 0; nt < 8; nt++) acc[nt] = (v4f){0.f, 0.f, 0.f, 0.f};

    #pragma unroll
    for (int kk = 0; kk < 4; kk++) {
        int kof = kk * 32 + quad * 8;
        v8s a = *(const v8s*)&As[m0 + mr][kof];
        #pragma unroll
        for (int nt = 0; nt < 8; nt++) {
            v8s b = *(const v8s*)&Bs[nt * 16 + mr][kof];
            acc[nt] = __builtin_amdgcn_mfma_f32_16x16x32_bf16(a, b, acc[nt], 0, 0, 0);
        }
    }

    #pragma unroll
    for (int nt = 0; nt < 8; nt++)
        #pragma unroll
        for (int r = 0; r < 4; r++)
            As[m0 + quad * 4 + r][nt * 16 + mr] = f2bf(acc[nt][r]);
    __syncthreads();
    {
        int row = m0 + (lane >> 2);
        int c0  = (lane & 3) * 32;        // 32 cols = one head
        int n = n0 + row;
        if (n < N_NODES) {
            float ds = 0.f, dd = 0.f;
            #pragma unroll
            for (int i = 0; i < 4; i++) {
                uint4 v = *(const uint4*)&As[row][c0 + i * 8];
                *(uint4*)&h16[(size_t)n * F_DIM + c0 + i * 8] = v;
                float f0 = lo2f(v.x), f1 = hi2f(v.x);
                float f2 = lo2f(v.y), f3 = hi2f(v.y);
                float f4 = lo2f(v.z), f5 = hi2f(v.z);
                float f6 = lo2f(v.w), f7 = hi2f(v.w);
                const float* ps = &attl[c0 + i * 8];
                const float* pd = &attl[128 + c0 + i * 8];
                ds += f0*ps[0] + f1*ps[1] + f2*ps[2] + f3*ps[3]
                    + f4*ps[4] + f5*ps[5] + f6*ps[6] + f7*ps[7];
                dd += f0*pd[0] + f1*pd[1] + f2*pd[2] + f3*pd[3]
                    + f4*pd[4] + f5*pd[5] + f6*pd[6] + f7*pd[7];
            }
            int hd = lane & 3;
            a_src[n * 4 + hd] = ds;
            a_dst[n * 4 + hd] = dd;
        }
    }
}

// ---------------- scan of padded degrees -> ebounds / cursor / pad slots -----
__global__ __launch_bounds__(256) void k_scanp(const int* __restrict__ deg,
                                               int* __restrict__ part) {
    int base = blockIdx.x * SC_CHUNK + threadIdx.x * 16;
    int s = 0;
    #pragma unroll
    for (int i = 0; i < 16; i++) {
        int idx = base + i;
        if (idx < N_PAD) s += (deg[idx] + 3) & ~3;
    }
    __shared__ int wsum[4];
    for (int off = 32; off >= 1; off >>= 1) s += __shfl_down(s, off, 64);
    if ((threadIdx.x & 63) == 0) wsum[threadIdx.x >> 6] = s;
    __syncthreads();
    if (threadIdx.x == 0) part[blockIdx.x] = wsum[0] + wsum[1] + wsum[2] + wsum[3];
}

// one-wave shuffle scan over SC_NB (<=64) partials
__global__ void k_scant(int* part) {
    int lane = threadIdx.x & 63;
    int v = (lane < SC_NB) ? part[lane] : 0;
    int x = v;
    #pragma unroll
    for (int off = 1; off < 64; off <<= 1) {
        int y = __shfl_up(x, off, 64);
        if (lane >= off) x += y;
    }
    if (lane < SC_NB) part[lane] = x - v;   // exclusive
}

__global__ __launch_bounds__(256) void k_scand(const int* __restrict__ deg,
                                               const int* __restrict__ part,
                                               int2* __restrict__ ebounds,
                                               int* __restrict__ cursor,
                                               int* __restrict__ csr2,
                                               __half* __restrict__ pbuf) {
    __shared__ int tsum[256];
    int tid  = threadIdx.x;
    int base = blockIdx.x * SC_CHUNK + tid * 16;
    int c[16]; int s = 0;
    #pragma unroll
    for (int i = 0; i < 16; i++) {
        int idx = base + i;
        c[i] = (idx < N_PAD) ? deg[idx] : 0;
        s += (c[i] + 3) & ~3;
    }
    tsum[tid] = s;
    __syncthreads();
    for (int off = 1; off < 256; off <<= 1) {
        int y = (tid >= off) ? tsum[tid - off] : 0;
        __syncthreads();
        tsum[tid] += y;
        __syncthreads();
    }
    int run = part[blockIdx.x] + tsum[tid] - s;
    #pragma unroll
    for (int i = 0; i < 16; i++) {
        int idx = base + i;
        if (idx < N_PAD) {
            int cc = c[i], cp = (cc + 3) & ~3;
            ebounds[idx] = make_int2(run, run + cc);
            cursor[idx]  = run;
            for (int k = cc; k < cp; k++) {      // pad slots: self idx, p = 0
                int pos = run + k;
                csr2[pos] = idx;
                *(uint2*)&pbuf[(size_t)pos * 4] = make_uint2(0u, 0u);
            }
            run += cp;
        }
    }
}

// ---------------- direct scatter: edge -> final CSR slot + exp weight --------
__global__ __launch_bounds__(1024) void k_scat(const int* __restrict__ ei,
                                               int* __restrict__ cursor,
                                               const float* __restrict__ a_src,
                                               const float* __restrict__ a_dst,
                                               int* __restrict__ csr2,
                                               __half* __restrict__ pbuf) {
    const int4* ps = (const int4*)(ei + blockIdx.x * EPS);
    const int4* pd = (const int4*)(ei + N_EDGES + blockIdx.x * EPS);
    #define PLACE(sv, dv) {                                                    \
        int pos = atomicAdd(&cursor[dv], 1);                                   \
        csr2[pos] = (sv);                                                      \
        float4 as = *(const float4*)&a_src[(sv) * 4];                          \
        float4 ad = *(const float4*)&a_dst[(dv) * 4];                          \
        float e0 = as.x + ad.x; e0 = e0 > 0.f ? e0 : NEG_SLOPE * e0;           \
        float e1 = as.y + ad.y; e1 = e1 > 0.f ? e1 : NEG_SLOPE * e1;           \
        float e2 = as.z + ad.z; e2 = e2 > 0.f ? e2 : NEG_SLOPE * e2;           \
        float e3 = as.w + ad.w; e3 = e3 > 0.f ? e3 : NEG_SLOPE * e3;           \
        __half2 lo = __floats2half2_rn(__expf(e0), __expf(e1));                \
        __half2 hi = __floats2half2_rn(__expf(e2), __expf(e3));                \
        *(uint2*)&pbuf[(size_t)pos * 4] =                                      \
            make_uint2(*(unsigned*)&lo, *(unsigned*)&hi);                      \
    }
    for (int i = threadIdx.x; i < EPS / 4; i += 1024) {
        int4 s4 = ps[i];
        int4 d4 = pd[i];
        PLACE(s4.x, d4.x);
        PLACE(s4.y, d4.y);
        PLACE(s4.z, d4.z);
        PLACE(s4.w, d4.w);
    }
    #undef PLACE
}

// ---------------- aggregation: one wave per dst, 4 edges/step, unroll 2 ------
// (reverted to the proven round-0 structure: unroll-4 raised VGPR 28->36 and
//  regressed 70.6->78.0us; random 256B gathers saturate ~3.7 TB/s here)
__global__ __launch_bounds__(256) void k_agg(const uint4* __restrict__ h16x4,
                                             const float* __restrict__ a_src,
                                             const float* __restrict__ a_dst,
                                             const int2* __restrict__ ebounds,
                                             const int* __restrict__ csr2,
                                             const __half* __restrict__ pbuf,
                                             const float* __restrict__ bias,
                                             float* __restrict__ out) {
    int n = (blockIdx.x * 256 + threadIdx.x) >> 6;
    if (n >= N_NODES) return;
    int lane = threadIdx.x & 63;
    int grp = lane >> 4, g = lane & 15, hd = g >> 2;

    float p0 = 0.f;
    if (grp == 0) {
        float e0 = a_src[n * 4 + hd] + a_dst[n * 4 + hd];
        e0 = e0 > 0.f ? e0 : NEG_SLOPE * e0;
        p0 = __expf(e0);                   // self-loop (group 0 only)
    }
    uint4 hs = h16x4[(size_t)n * 16 + g];
    float l  = p0;
    float a0 = p0 * lo2f(hs.x), a1 = p0 * hi2f(hs.x);
    float a2 = p0 * lo2f(hs.y), a3 = p0 * hi2f(hs.y);
    float a4 = p0 * lo2f(hs.z), a5 = p0 * hi2f(hs.z);
    float a6 = p0 * lo2f(hs.w), a7 = p0 * hi2f(hs.w);

    int2 eb = ebounds[n];
    int beg = eb.x, cnt = eb.y - eb.x;
    const int* sp = csr2 + beg + grp;
    const __half* pp = pbuf + (size_t)(beg + grp) * 4 + hd;
    int steps = (cnt + 3) >> 2;
    int t = 0;
    for (; t + 2 <= steps; t += 2) {
        int s0 = sp[4 * t];
        int s1 = sp[4 * t + 4];
        float q0 = __half2float(pp[16 * t]);
        float q1 = __half2float(pp[16 * t + 16]);
        uint4 h0 = h16x4[(size_t)s0 * 16 + g];
        uint4 h1 = h16x4[(size_t)s1 * 16 + g];
        l  += q0 + q1;
        a0 += q0 * lo2f(h0.x) + q1 * lo2f(h1.x);
        a1 += q0 * hi2f(h0.x) + q1 * hi2f(h1.x);
        a2 += q0 * lo2f(h0.y) + q1 * lo2f(h1.y);
        a3 += q0 * hi2f(h0.y) + q1 * hi2f(h1.y);
        a4 += q0 * lo2f(h0.z) + q1 * lo2f(h1.z);
        a5 += q0 * hi2f(h0.z) + q1 * hi2f(h1.z);
        a6 += q0 * lo2f(h0.w) + q1 * lo2f(h1.w);
        a7 += q0 * hi2f(h0.w) + q1 * hi2f(h1.w);
    }
    if (t < steps) {
        int s0 = sp[4 * t];
        float q0 = __half2float(pp[16 * t]);
        uint4 h0 = h16x4[(size_t)s0 * 16 + g];
        l  += q0;
        a0 += q0 * lo2f(h0.x);
        a1 += q0 * hi2f(h0.x);
        a2 += q0 * lo2f(h0.y);
        a3 += q0 * hi2f(h0.y);
        a4 += q0 * lo2f(h0.z);
        a5 += q0 * hi2f(h0.z);
        a6 += q0 * lo2f(h0.w);
        a7 += q0 * hi2f(h0.w);
    }
    #define RED2(v) v += __shfl_xor(v, 16, 64); v += __shfl_xor(v, 32, 64);
    RED2(l); RED2(a0); RED2(a1); RED2(a2); RED2(a3);
    RED2(a4); RED2(a5); RED2(a6); RED2(a7);
    #undef RED2

    if (grp == 0) {
        float inv = 1.f / (l + 1e-16f);
        float4 b0 = *(const float4*)&bias[g * 8];
        float4 b1 = *(const float4*)&bias[g * 8 + 4];
        float o0 = a0 * inv + b0.x, o1 = a1 * inv + b0.y;
        float o2 = a2 * inv + b0.z, o3 = a3 * inv + b0.w;
        float o4 = a4 * inv + b1.x, o5 = a5 * inv + b1.y;
        float o6 = a6 * inv + b1.z, o7 = a7 * inv + b1.w;
        // branchless ELU via fast exp
        o0 = o0 > 0.f ? o0 : __expf(o0) - 1.f;
        o1 = o1 > 0.f ? o1 : __expf(o1) - 1.f;
        o2 = o2 > 0.f ? o2 : __expf(o2) - 1.f;
        o3 = o3 > 0.f ? o3 : __expf(o3) - 1.f;
        o4 = o4 > 0.f ? o4 : __expf(o4) - 1.f;
        o5 = o5 > 0.f ? o5 : __expf(o5) - 1.f;
        o6 = o6 > 0.f ? o6 : __expf(o6) - 1.f;
        o7 = o7 > 0.f ? o7 : __expf(o7) - 1.f;
        *(float4*)&out[(size_t)n * F_DIM + g * 8]     = make_float4(o0, o1, o2, o3);
        *(float4*)&out[(size_t)n * F_DIM + g * 8 + 4] = make_float4(o4, o5, o6, o7);
    }
}

extern "C" void kernel_launch(void* const* d_in, const int* in_sizes, int n_in,
                              void* d_out, int out_size, void* d_ws, size_t ws_size,
                              hipStream_t stream) {
    const float* x       = (const float*)d_in[0];
    const int*   ei      = (const int*)d_in[1];   // (2, E) row-major int32
    const float* W       = (const float*)d_in[2];
    const float* att_src = (const float*)d_in[3];
    const float* att_dst = (const float*)d_in[4];
    const float* bias    = (const float*)d_in[5];
    float*       out     = (float*)d_out;

    char* ws = (char*)d_ws;
    unsigned short* h16 = (unsigned short*)ws; ws += (size_t)N_NODES * F_DIM * 2;   // 25.6 MB
    float* a_src  = (float*)ws; ws += (size_t)N_PAD * 16;
    float* a_dst  = (float*)ws; ws += (size_t)N_PAD * 16;
    int*   deg    = (int*)ws;   ws += (size_t)N_PAD * 4;
    int*   cursor = (int*)ws;   ws += (size_t)N_PAD * 4;
    int2*  ebounds= (int2*)ws;  ws += (size_t)N_PAD * 8;
    int*   part   = (int*)ws;   ws += 1024;
    int*   csr2   = (int*)ws;   ws += (size_t)CSR_CAP * 4;                          // 7.6 MB
    __half* pbuf  = (__half*)ws; ws += (size_t)CSR_CAP * 8;                         // 15.2 MB

    hipMemsetAsync(deg, 0, (size_t)N_PAD * 4, stream);
    k_main<<<GB + HB, 256, 0, stream>>>(x, W, ei + N_EDGES, h16, att_src, att_dst,
                                        a_src, a_dst, deg);
    k_scanp<<<SC_NB, 256, 0, stream>>>(deg, part);
    k_scant<<<1, 64, 0, stream>>>(part);
    k_scand<<<SC_NB, 256, 0, stream>>>(deg, part, ebounds, cursor, csr2, pbuf);
    k_scat<<<SB, 1024, 0, stream>>>(ei, cursor, a_src, a_dst, csr2, pbuf);
    k_agg<<<(N_NODES * 64 + 255) / 256, 256, 0, stream>>>((const uint4*)h16, a_src, a_dst, ebounds, csr2, pbuf, bias, out);
}

// Round 3
// 255.356 us; speedup vs baseline: 1.5455x; 1.5455x over previous
//
#include <hip/hip_runtime.h>
#include <hip/hip_fp16.h>
#include <math.h>

#define N_NODES 100000
#define N_EDGES 1600000
#define IN_DIM 128
#define F_DIM 128      // HEADS*OUT_DIM
#define NEG_SLOPE 0.2f

// ---- atomic-free CSR build parameters (two-level bucket sort: proven) ----
#define BUCKW_LOG 7            // 128 nodes per bucket
#define NBUCK 784              // covers 100352 >= N_NODES
#define NBLK 128               // blocks in bucket passes (keeps 64B ebuf write streams)
#define EPB 12500              // edges per block (NBLK*EPB == N_EDGES)
#define G_TOT (NBUCK * NBLK)   // 100352
#define SC_CHUNK 4096
#define SC_NB ((G_TOT + SC_CHUNK - 1) / SC_CHUNK)   // 25 (fits one wave in k_scant)
#define CSR_CAP (N_EDGES + NBUCK * 384)             // pad-to-4 slots (<=3/node)
#define PADBIT 0x80000000u

typedef short v8s __attribute__((ext_vector_type(8)));
typedef float v4f __attribute__((ext_vector_type(4)));

static __device__ __forceinline__ unsigned short f2bf(float f) {
    unsigned u = __float_as_uint(f);
    u += 0x7fffu + ((u >> 16) & 1u);
    return (unsigned short)(u >> 16);
}
static __device__ __forceinline__ float lo2f(unsigned u) { return __uint_as_float(u << 16); }
static __device__ __forceinline__ float hi2f(unsigned u) { return __uint_as_float(u & 0xffff0000u); }

// ---------------- W prep: Wt[n][k] = bf16(W[k][n]) ---------------------------
__global__ __launch_bounds__(256) void k_wprep(const float* __restrict__ W,
                                               unsigned short* __restrict__ Wt) {
    int i = blockIdx.x * 256 + threadIdx.x;   // 16384
    int n = i >> 7, k = i & 127;
    Wt[n * 128 + k] = f2bf(W[k * 128 + n]);
}

// ---------------- GEMM: h16 = bf16(x @ W) via MFMA, fused a_src/a_dst --------
__global__ __launch_bounds__(256) void k_gemm(const float* __restrict__ x,
                                              const unsigned short* __restrict__ Wt,
                                              unsigned short* __restrict__ h16,
                                              const float* __restrict__ att_src,
                                              const float* __restrict__ att_dst,
                                              float* __restrict__ a_src,
                                              float* __restrict__ a_dst) {
    __shared__ unsigned short As[64][136];    // [row][k]
    __shared__ unsigned short Bs[128][136];   // [n][k]
    __shared__ float attl[256];               // [0..127]=att_src, [128..255]=att_dst
    const int t  = threadIdx.x;
    const int n0 = blockIdx.x * 64;

    attl[t] = (t < 128) ? att_src[t] : att_dst[t - 128];

    {
        int row = t >> 2, k0 = (t & 3) * 32;
        int n = n0 + row;
        #pragma unroll
        for (int i = 0; i < 4; i++) {
            float4 va = make_float4(0.f,0.f,0.f,0.f), vb = va;
            if (n < N_NODES) {
                const float* p = x + (size_t)n * IN_DIM + k0 + i * 8;
                va = *(const float4*)p;
                vb = *(const float4*)(p + 4);
            }
            uint4 u;
            u.x = f2bf(va.x) | ((unsigned)f2bf(va.y) << 16);
            u.y = f2bf(va.z) | ((unsigned)f2bf(va.w) << 16);
            u.z = f2bf(vb.x) | ((unsigned)f2bf(vb.y) << 16);
            u.w = f2bf(vb.z) | ((unsigned)f2bf(vb.w) << 16);
            *(uint4*)&As[row][k0 + i * 8] = u;
        }
    }
    {
        int nr = t >> 1, s0 = (t & 1) * 64;
        const uint4* src = (const uint4*)(Wt + nr * 128 + s0);
        #pragma unroll
        for (int i = 0; i < 8; i++)
            *(uint4*)&Bs[nr][s0 + i * 8] = src[i];
    }
    __syncthreads();

    const int w = t >> 6, lane = t & 63;
    const int mr = lane & 15, quad = lane >> 4;
    const int m0 = w * 16;

    v4f acc[8];
    #pragma unroll
    for (int nt = 0; nt < 8; nt++) acc[nt] = (v4f){0.f, 0.f, 0.f, 0.f};

    #pragma unroll
    for (int kk = 0; kk < 4; kk++) {
        int kof = kk * 32 + quad * 8;
        v8s a = *(const v8s*)&As[m0 + mr][kof];
        #pragma unroll
        for (int nt = 0; nt < 8; nt++) {
            v8s b = *(const v8s*)&Bs[nt * 16 + mr][kof];
            acc[nt] = __builtin_amdgcn_mfma_f32_16x16x32_bf16(a, b, acc[nt], 0, 0, 0);
        }
    }

    #pragma unroll
    for (int nt = 0; nt < 8; nt++)
        #pragma unroll
        for (int r = 0; r < 4; r++)
            As[m0 + quad * 4 + r][nt * 16 + mr] = f2bf(acc[nt][r]);
    __syncthreads();
    {
        int row = m0 + (lane >> 2);
        int c0  = (lane & 3) * 32;        // 32 cols = one head
        int n = n0 + row;
        if (n < N_NODES) {
            float ds = 0.f, dd = 0.f;
            #pragma unroll
            for (int i = 0; i < 4; i++) {
                uint4 v = *(const uint4*)&As[row][c0 + i * 8];
                *(uint4*)&h16[(size_t)n * F_DIM + c0 + i * 8] = v;
                float f0 = lo2f(v.x), f1 = hi2f(v.x);
                float f2 = lo2f(v.y), f3 = hi2f(v.y);
                float f4 = lo2f(v.z), f5 = hi2f(v.z);
                float f6 = lo2f(v.w), f7 = hi2f(v.w);
                const float* ps = &attl[c0 + i * 8];
                const float* pd = &attl[128 + c0 + i * 8];
                ds += f0*ps[0] + f1*ps[1] + f2*ps[2] + f3*ps[3]
                    + f4*ps[4] + f5*ps[5] + f6*ps[6] + f7*ps[7];
                dd += f0*pd[0] + f1*pd[1] + f2*pd[2] + f3*pd[3]
                    + f4*pd[4] + f5*pd[5] + f6*pd[6] + f7*pd[7];
            }
            int hd = lane & 3;
            a_src[n * 4 + hd] = ds;
            a_dst[n * 4 + hd] = dd;
        }
    }
}

// ---------------- CSR build, atomic-free (two-level counting sort) -----------
__global__ __launch_bounds__(1024) void k_bhist(const int* __restrict__ ei_dst,
                                                int* __restrict__ G) {
    __shared__ int hist[NBUCK];
    for (int i = threadIdx.x; i < NBUCK; i += 1024) hist[i] = 0;
    __syncthreads();
    const int4* p = (const int4*)(ei_dst + blockIdx.x * EPB);
    const int n4 = EPB / 4;   // 3125
    for (int i = threadIdx.x; i < n4; i += 1024) {
        int4 d = p[i];
        atomicAdd(&hist[d.x >> BUCKW_LOG], 1);
        atomicAdd(&hist[d.y >> BUCKW_LOG], 1);
        atomicAdd(&hist[d.z >> BUCKW_LOG], 1);
        atomicAdd(&hist[d.w >> BUCKW_LOG], 1);
    }
    __syncthreads();
    for (int b = threadIdx.x; b < NBUCK; b += 1024)
        G[b * NBLK + blockIdx.x] = hist[b];
}

__global__ __launch_bounds__(256) void k_scanp(const int* __restrict__ a,
                                               int* __restrict__ part) {
    int base = blockIdx.x * SC_CHUNK + threadIdx.x * 16;
    int s = 0;
    #pragma unroll
    for (int i = 0; i < 16; i++) {
        int idx = base + i;
        if (idx < G_TOT) s += a[idx];
    }
    __shared__ int wsum[4];
    for (int off = 32; off >= 1; off >>= 1) s += __shfl_down(s, off, 64);
    if ((threadIdx.x & 63) == 0) wsum[threadIdx.x >> 6] = s;
    __syncthreads();
    if (threadIdx.x == 0) part[blockIdx.x] = wsum[0] + wsum[1] + wsum[2] + wsum[3];
}

// one-wave shuffle scan over SC_NB (<=64) partials
__global__ void k_scant(int* part, int* boff) {
    int lane = threadIdx.x & 63;
    int v = (lane < SC_NB) ? part[lane] : 0;
    int x = v;
    #pragma unroll
    for (int off = 1; off < 64; off <<= 1) {
        int y = __shfl_up(x, off, 64);
        if (lane >= off) x += y;
    }
    if (lane < SC_NB) part[lane] = x - v;   // exclusive
    if (lane == 0) boff[NBUCK] = N_EDGES;
}

__global__ __launch_bounds__(256) void k_scand(int* __restrict__ a,
                                               const int* __restrict__ part,
                                               int* __restrict__ boff) {
    __shared__ int tsum[256];
    int tid  = threadIdx.x;
    int base = blockIdx.x * SC_CHUNK + tid * 16;
    int v[16]; int s = 0;
    #pragma unroll
    for (int i = 0; i < 16; i++) {
        int idx = base + i;
        v[i] = (idx < G_TOT) ? a[idx] : 0;
        s += v[i];
    }
    tsum[tid] = s;
    __syncthreads();
    for (int off = 1; off < 256; off <<= 1) {
        int y = (tid >= off) ? tsum[tid - off] : 0;
        __syncthreads();
        tsum[tid] += y;
        __syncthreads();
    }
    int run = part[blockIdx.x] + tsum[tid] - s;
    #pragma unroll
    for (int i = 0; i < 16; i++) {
        int idx = base + i;
        if (idx < G_TOT) {
            a[idx] = run;
            if (idx % NBLK == 0) boff[idx / NBLK] = run;
        }
        run += v[i];
    }
}

// Pass C: scatter edges into bucket-grouped ebuf (pack src | local_dst<<17)
__global__ __launch_bounds__(1024) void k_bscat(const int* __restrict__ ei,
                                                const int* __restrict__ G,
                                                int* __restrict__ ebuf) {
    __shared__ int base[NBUCK];
    for (int b = threadIdx.x; b < NBUCK; b += 1024)
        base[b] = G[b * NBLK + blockIdx.x];
    __syncthreads();
    const int4* ps = (const int4*)(ei + blockIdx.x * EPB);
    const int4* pd = (const int4*)(ei + N_EDGES + blockIdx.x * EPB);
    const int n4 = EPB / 4;
    for (int i = threadIdx.x; i < n4; i += 1024) {
        int4 s = ps[i];
        int4 d = pd[i];
        int b0 = d.x >> BUCKW_LOG; int p0 = atomicAdd(&base[b0], 1);
        ebuf[p0] = s.x | ((d.x & 127) << 17);
        int b1 = d.y >> BUCKW_LOG; int p1 = atomicAdd(&base[b1], 1);
        ebuf[p1] = s.y | ((d.y & 127) << 17);
        int b2 = d.z >> BUCKW_LOG; int p2 = atomicAdd(&base[b2], 1);
        ebuf[p2] = s.z | ((d.z & 127) << 17);
        int b3 = d.w >> BUCKW_LOG; int p3 = atomicAdd(&base[b3], 1);
        ebuf[p3] = s.w | ((d.w & 127) << 17);
    }
}

// Pass D: finalize CSR only (no weights — computed inline in k_agg now).
// Pad slots carry PADBIT so k_agg zeroes their contribution.
__global__ __launch_bounds__(512) void k_csrfin(const int* __restrict__ ebuf,
                                                const int* __restrict__ boff,
                                                int2* __restrict__ ebounds,
                                                int* __restrict__ csr2) {
    __shared__ int cnt[128];
    __shared__ int off[128];
    __shared__ int wtot;
    int b = blockIdx.x;
    int beg = boff[b], end = boff[b + 1];
    int padded_base = beg + b * 384;     // reserve 3 pad slots per node
    int tid = threadIdx.x;
    if (tid < 128) cnt[tid] = 0;
    __syncthreads();
    {
        int j = beg + tid;
        for (; j + 3 * 512 < end; j += 4 * 512) {
            int e0 = ebuf[j];
            int e1 = ebuf[j + 512];
            int e2 = ebuf[j + 1024];
            int e3 = ebuf[j + 1536];
            atomicAdd(&cnt[(e0 >> 17) & 127], 1);
            atomicAdd(&cnt[(e1 >> 17) & 127], 1);
            atomicAdd(&cnt[(e2 >> 17) & 127], 1);
            atomicAdd(&cnt[(e3 >> 17) & 127], 1);
        }
        for (; j < end; j += 512)
            atomicAdd(&cnt[(ebuf[j] >> 17) & 127], 1);
    }
    __syncthreads();
    // parallel exclusive scan of padded counts (128 entries across 2 waves)
    if (tid < 128) {
        int cp = (cnt[tid] + 3) & ~3;
        int x = cp;
        #pragma unroll
        for (int o = 1; o < 64; o <<= 1) {
            int y = __shfl_up(x, o, 64);
            if ((tid & 63) >= o) x += y;
        }
        off[tid] = x - cp;                 // exclusive within wave
        if (tid == 63) wtot = x;           // wave-0 inclusive total
    }
    __syncthreads();
    if (tid < 128) {
        int v = off[tid] + ((tid >= 64) ? wtot : 0) + padded_base;
        off[tid] = v;
        int node = (b << BUCKW_LOG) + tid;
        int c = cnt[tid];
        if (node < N_NODES) {
            ebounds[node] = make_int2(v, v + c);
            int cpad = (c + 3) & ~3;
            for (int k = c; k < cpad; k++)       // pad slots: self idx + PADBIT
                csr2[v + k] = node | PADBIT;
        }
        cnt[tid] = 0;               // reuse as cursors
    }
    __syncthreads();
    {
        int j = beg + tid;
        for (; j + 3 * 512 < end; j += 4 * 512) {
            int e0 = ebuf[j];
            int e1 = ebuf[j + 512];
            int e2 = ebuf[j + 1024];
            int e3 = ebuf[j + 1536];
            int d0 = (e0 >> 17) & 127; int r0 = atomicAdd(&cnt[d0], 1);
            csr2[off[d0] + r0] = e0 & 0x1ffff;
            int d1 = (e1 >> 17) & 127; int r1 = atomicAdd(&cnt[d1], 1);
            csr2[off[d1] + r1] = e1 & 0x1ffff;
            int d2 = (e2 >> 17) & 127; int r2 = atomicAdd(&cnt[d2], 1);
            csr2[off[d2] + r2] = e2 & 0x1ffff;
            int d3 = (e3 >> 17) & 127; int r3 = atomicAdd(&cnt[d3], 1);
            csr2[off[d3] + r3] = e3 & 0x1ffff;
        }
        for (; j < end; j += 512) {
            int e0 = ebuf[j];
            int d0 = (e0 >> 17) & 127; int r0 = atomicAdd(&cnt[d0], 1);
            csr2[off[d0] + r0] = e0 & 0x1ffff;
        }
    }
}

// ---------------- aggregation: one wave per dst, 4 edges/step, unroll 2 ------
// Weights computed inline: q = exp(leakyrelu(a_src[s] + a_dst[n])); a_dst[n]
// is wave-constant, a_src[s] gather (16B) rides along the 256B h16[s] gather.
__global__ __launch_bounds__(256) void k_agg(const uint4* __restrict__ h16x4,
                                             const float* __restrict__ a_src,
                                             const float* __restrict__ a_dst,
                                             const int2* __restrict__ ebounds,
                                             const int* __restrict__ csr2,
                                             const float* __restrict__ bias,
                                             float* __restrict__ out) {
    int n = (blockIdx.x * 256 + threadIdx.x) >> 6;
    if (n >= N_NODES) return;
    int lane = threadIdx.x & 63;
    int grp = lane >> 4, g = lane & 15, hd = g >> 2;

    float adn = a_dst[n * 4 + hd];         // wave-constant per head
    float p0 = 0.f;
    if (grp == 0) {
        float e0 = a_src[n * 4 + hd] + adn;
        e0 = e0 > 0.f ? e0 : NEG_SLOPE * e0;
        p0 = __expf(e0);                   // self-loop (group 0 only)
    }
    uint4 hs = h16x4[(size_t)n * 16 + g];
    float l  = p0;
    float a0 = p0 * lo2f(hs.x), a1 = p0 * hi2f(hs.x);
    float a2 = p0 * lo2f(hs.y), a3 = p0 * hi2f(hs.y);
    float a4 = p0 * lo2f(hs.z), a5 = p0 * hi2f(hs.z);
    float a6 = p0 * lo2f(hs.w), a7 = p0 * hi2f(hs.w);

    int2 eb = ebounds[n];
    int beg = eb.x, cnt = eb.y - eb.x;
    const int* sp = csr2 + beg + grp;
    int steps = (cnt + 3) >> 2;
    int t = 0;
    for (; t + 2 <= steps; t += 2) {
        int u0 = sp[4 * t];
        int u1 = sp[4 * t + 4];
        int s0 = u0 & 0x7fffffff;
        int s1 = u1 & 0x7fffffff;
        float w0 = a_src[s0 * 4 + hd] + adn;
        float w1 = a_src[s1 * 4 + hd] + adn;
        uint4 h0 = h16x4[(size_t)s0 * 16 + g];
        uint4 h1 = h16x4[(size_t)s1 * 16 + g];
        w0 = w0 > 0.f ? w0 : NEG_SLOPE * w0;
        w1 = w1 > 0.f ? w1 : NEG_SLOPE * w1;
        float q0 = __expf(w0);
        float q1 = __expf(w1);
        q0 = u0 < 0 ? 0.f : q0;            // pad slot -> zero weight
        q1 = u1 < 0 ? 0.f : q1;
        l  += q0 + q1;
        a0 += q0 * lo2f(h0.x) + q1 * lo2f(h1.x);
        a1 += q0 * hi2f(h0.x) + q1 * hi2f(h1.x);
        a2 += q0 * lo2f(h0.y) + q1 * lo2f(h1.y);
        a3 += q0 * hi2f(h0.y) + q1 * hi2f(h1.y);
        a4 += q0 * lo2f(h0.z) + q1 * lo2f(h1.z);
        a5 += q0 * hi2f(h0.z) + q1 * hi2f(h1.z);
        a6 += q0 * lo2f(h0.w) + q1 * lo2f(h1.w);
        a7 += q0 * hi2f(h0.w) + q1 * hi2f(h1.w);
    }
    if (t < steps) {
        int u0 = sp[4 * t];
        int s0 = u0 & 0x7fffffff;
        float w0 = a_src[s0 * 4 + hd] + adn;
        uint4 h0 = h16x4[(size_t)s0 * 16 + g];
        w0 = w0 > 0.f ? w0 : NEG_SLOPE * w0;
        float q0 = __expf(w0);
        q0 = u0 < 0 ? 0.f : q0;
        l  += q0;
        a0 += q0 * lo2f(h0.x);
        a1 += q0 * hi2f(h0.x);
        a2 += q0 * lo2f(h0.y);
        a3 += q0 * hi2f(h0.y);
        a4 += q0 * lo2f(h0.z);
        a5 += q0 * hi2f(h0.z);
        a6 += q0 * lo2f(h0.w);
        a7 += q0 * hi2f(h0.w);
    }
    #define RED2(v) v += __shfl_xor(v, 16, 64); v += __shfl_xor(v, 32, 64);
    RED2(l); RED2(a0); RED2(a1); RED2(a2); RED2(a3);
    RED2(a4); RED2(a5); RED2(a6); RED2(a7);
    #undef RED2

    if (grp == 0) {
        float inv = 1.f / (l + 1e-16f);
        float4 b0 = *(const float4*)&bias[g * 8];
        float4 b1 = *(const float4*)&bias[g * 8 + 4];
        float o0 = a0 * inv + b0.x, o1 = a1 * inv + b0.y;
        float o2 = a2 * inv + b0.z, o3 = a3 * inv + b0.w;
        float o4 = a4 * inv + b1.x, o5 = a5 * inv + b1.y;
        float o6 = a6 * inv + b1.z, o7 = a7 * inv + b1.w;
        // branchless ELU via fast exp
        o0 = o0 > 0.f ? o0 : __expf(o0) - 1.f;
        o1 = o1 > 0.f ? o1 : __expf(o1) - 1.f;
        o2 = o2 > 0.f ? o2 : __expf(o2) - 1.f;
        o3 = o3 > 0.f ? o3 : __expf(o3) - 1.f;
        o4 = o4 > 0.f ? o4 : __expf(o4) - 1.f;
        o5 = o5 > 0.f ? o5 : __expf(o5) - 1.f;
        o6 = o6 > 0.f ? o6 : __expf(o6) - 1.f;
        o7 = o7 > 0.f ? o7 : __expf(o7) - 1.f;
        *(float4*)&out[(size_t)n * F_DIM + g * 8]     = make_float4(o0, o1, o2, o3);
        *(float4*)&out[(size_t)n * F_DIM + g * 8 + 4] = make_float4(o4, o5, o6, o7);
    }
}

extern "C" void kernel_launch(void* const* d_in, const int* in_sizes, int n_in,
                              void* d_out, int out_size, void* d_ws, size_t ws_size,
                              hipStream_t stream) {
    const float* x       = (const float*)d_in[0];
    const int*   ei      = (const int*)d_in[1];   // (2, E) row-major int32
    const float* W       = (const float*)d_in[2];
    const float* att_src = (const float*)d_in[3];
    const float* att_dst = (const float*)d_in[4];
    const float* bias    = (const float*)d_in[5];
    float*       out     = (float*)d_out;

    char* ws = (char*)d_ws;
    unsigned short* h16 = (unsigned short*)ws; ws += (size_t)N_NODES * F_DIM * 2;   // 25.6 MB
    unsigned short* Wt  = (unsigned short*)ws; ws += (size_t)IN_DIM * F_DIM * 2;    // 32 KB
    float* a_src  = (float*)ws; ws += (size_t)N_NODES * 4 * 4;
    float* a_dst  = (float*)ws; ws += (size_t)N_NODES * 4 * 4;
    int*   G      = (int*)ws;   ws += (size_t)G_TOT * 4;                            // 0.4 MB
    int*   part   = (int*)ws;   ws += 1024;
    int*   boff   = (int*)ws;   ws += 4096;
    int2*  ebounds= (int2*)ws;  ws += (size_t)N_NODES * 8 + 512;
    int*   ebuf   = (int*)ws;   ws += (size_t)N_EDGES * 4;                          // 6.4 MB
    int*   csr2   = (int*)ws;   ws += (size_t)CSR_CAP * 4;                          // 7.6 MB

    k_wprep<<<64, 256, 0, stream>>>(W, Wt);
    k_gemm<<<(N_NODES + 63) / 64, 256, 0, stream>>>(x, Wt, h16, att_src, att_dst, a_src, a_dst);

    k_bhist<<<NBLK, 1024, 0, stream>>>(ei + N_EDGES, G);
    k_scanp<<<SC_NB, 256, 0, stream>>>(G, part);
    k_scant<<<1, 64, 0, stream>>>(part, boff);
    k_scand<<<SC_NB, 256, 0, stream>>>(G, part, boff);
    k_bscat<<<NBLK, 1024, 0, stream>>>(ei, G, ebuf);
    k_csrfin<<<NBUCK, 512, 0, stream>>>(ebuf, boff, ebounds, csr2);

    k_agg<<<(N_NODES * 64 + 255) / 256, 256, 0, stream>>>((const uint4*)h16, a_src, a_dst, ebounds, csr2, bias, out);
}